// Round 3
// baseline (573.962 us; speedup 1.0000x reference)
//
#include <hip/hip_runtime.h>
#include <hip/hip_bf16.h>

typedef __bf16  bf8_t  __attribute__((ext_vector_type(8)));
typedef float   f4_t   __attribute__((ext_vector_type(4)));
typedef unsigned int u32;

#define NB 32768

__device__ __forceinline__ float rcp_(float x)   { return __builtin_amdgcn_rcpf(x); }
__device__ __forceinline__ float sigf(float x)   { return rcp_(1.0f + __expf(-x)); }
__device__ __forceinline__ float tanhf_(float x) { return 1.0f - 2.0f * rcp_(1.0f + __expf(2.0f * x)); }

#define MFMA16(a, b, c) __builtin_amdgcn_mfma_f32_16x16x32_bf16((a), (b), (c), 0, 0, 0)

// ---------------- kA: layer-1 batch stats (deterministic partials) ----------------
__global__ __launch_bounds__(128) void kA(
    const float* __restrict__ x, const float* __restrict__ W1,
    float* __restrict__ part1)
{
  __shared__ float w1t[64 * 32];
  __shared__ float hbuf[128 * 36];
  __shared__ float sred[2][64];
  const int tid = threadIdx.x;
  const int t = blockIdx.x >> 8, chunk = blockIdx.x & 255;
  const int row = chunk * 128 + tid;

  #pragma unroll
  for (int i = 0; i < 16; ++i) { int e = tid * 16 + i; w1t[(e & 63) * 32 + (e >> 6)] = W1[e]; }
  __syncthreads();

  const f4_t* xrow = (const f4_t*)(x + ((size_t)t * NB + row) * 64);
  f4_t acc[8];
  #pragma unroll
  for (int jq = 0; jq < 8; ++jq) acc[jq] = (f4_t){0.f, 0.f, 0.f, 0.f};
  #pragma unroll
  for (int k4 = 0; k4 < 16; ++k4) {
    f4_t xc = xrow[k4];
    #pragma unroll
    for (int kk = 0; kk < 4; ++kk) {
      const float xs = xc[kk];
      const f4_t* wr = (const f4_t*)&w1t[(k4 * 4 + kk) * 32];
      #pragma unroll
      for (int jq = 0; jq < 8; ++jq) acc[jq] += xs * wr[jq];
    }
  }
  #pragma unroll
  for (int jq = 0; jq < 8; ++jq) *(f4_t*)&hbuf[tid * 36 + jq * 4] = acc[jq];
  __syncthreads();
  if (tid < 64) {
    const int j = tid & 31, p = tid >> 5;
    float s = 0.f, q = 0.f;
    #pragma unroll 8
    for (int r = 0; r < 64; ++r) { float v = hbuf[(p * 64 + r) * 36 + j]; s += v; q += v * v; }
    sred[0][tid] = s; sred[1][tid] = q;
  }
  __syncthreads();
  if (tid < 64) {
    const int j = tid & 31, q = tid >> 5;
    part1[(t * 256 + chunk) * 64 + q * 32 + j] = sred[q][j] + sred[q][32 + j];
  }
}

// ---------------- kC: finalize scales1, layer-2 batch stats ----------------
__global__ __launch_bounds__(128) void kC(
    const float* __restrict__ x,
    const float* __restrict__ W1, const float* __restrict__ W2,
    const float* __restrict__ g1, const float* __restrict__ be1,
    const float* __restrict__ part1, float* __restrict__ part2,
    float* __restrict__ sc1sh1)
{
  __shared__ float w1t[64 * 32];
  __shared__ float w2t[32 * 32];
  __shared__ float hbuf[128 * 36];
  __shared__ float sred[2][64];
  __shared__ float s1[64];
  const int tid = threadIdx.x;
  const int t = blockIdx.x >> 8, chunk = blockIdx.x & 255;
  const int row = chunk * 128 + tid;

  #pragma unroll
  for (int i = 0; i < 16; ++i) { int e = tid * 16 + i; w1t[(e & 63) * 32 + (e >> 6)] = W1[e]; }
  #pragma unroll
  for (int i = 0; i < 8; ++i) { int e = tid * 8 + i; w2t[(e & 31) * 32 + (e >> 5)] = W2[e]; }
  if (tid < 64) {   // reduce part1 for this frame
    const int j = tid & 31, q = tid >> 5;
    float s = 0.f;
    for (int c = 0; c < 256; ++c) s += part1[(t * 256 + c) * 64 + q * 32 + j];
    sred[q][j] = s;
  }
  __syncthreads();
  if (tid < 32) {
    float mean = sred[0][tid] * (1.f / NB);
    float var  = sred[1][tid] * (1.f / NB) - mean * mean;
    float sc = g1[tid] * rsqrtf(var + 1e-5f);
    float sh = be1[tid] - mean * sc;
    s1[tid] = sc; s1[32 + tid] = sh;
    sc1sh1[t * 64 + tid] = sc; sc1sh1[t * 64 + 32 + tid] = sh;  // benign identical-value race
  }
  __syncthreads();

  const f4_t* xrow = (const f4_t*)(x + ((size_t)t * NB + row) * 64);
  f4_t acc[8];
  #pragma unroll
  for (int jq = 0; jq < 8; ++jq) acc[jq] = (f4_t){0.f, 0.f, 0.f, 0.f};
  #pragma unroll
  for (int k4 = 0; k4 < 16; ++k4) {
    f4_t xc = xrow[k4];
    #pragma unroll
    for (int kk = 0; kk < 4; ++kk) {
      const float xs = xc[kk];
      const f4_t* wr = (const f4_t*)&w1t[(k4 * 4 + kk) * 32];
      #pragma unroll
      for (int jq = 0; jq < 8; ++jq) acc[jq] += xs * wr[jq];
    }
  }
  float a1[32];
  #pragma unroll
  for (int jq = 0; jq < 8; ++jq)
    #pragma unroll
    for (int c = 0; c < 4; ++c) {
      int j = jq * 4 + c;
      a1[j] = fmaxf(acc[jq][c] * s1[j] + s1[32 + j], 0.f);
    }
  f4_t acc2[8];
  #pragma unroll
  for (int jq = 0; jq < 8; ++jq) acc2[jq] = (f4_t){0.f, 0.f, 0.f, 0.f};
  #pragma unroll
  for (int k = 0; k < 32; ++k) {
    const float a = a1[k];
    const f4_t* wr = (const f4_t*)&w2t[k * 32];
    #pragma unroll
    for (int jq = 0; jq < 8; ++jq) acc2[jq] += a * wr[jq];
  }
  #pragma unroll
  for (int jq = 0; jq < 8; ++jq) *(f4_t*)&hbuf[tid * 36 + jq * 4] = acc2[jq];
  __syncthreads();
  if (tid < 64) {
    const int j = tid & 31, p = tid >> 5;
    float s = 0.f, q = 0.f;
    #pragma unroll 8
    for (int r = 0; r < 64; ++r) { float v = hbuf[(p * 64 + r) * 36 + j]; s += v; q += v * v; }
    sred[0][tid] = s; sred[1][tid] = q;
  }
  __syncthreads();
  if (tid < 64) {
    const int j = tid & 31, q = tid >> 5;
    part2[(t * 256 + chunk) * 64 + q * 32 + j] = sred[q][j] + sred[q][32 + j];
  }
}

// ---------------- k_main: fused MLP encode + 28-step LSTM ----------------
__device__ __forceinline__ void cell_update(
    f4_t gi, f4_t gf, f4_t gg, f4_t go, f4_t& c,
    char* hnxt, float* __restrict__ out, const int* ob,
    int mt, int lh, int hcol, bool dostore, int soff)
{
  #pragma unroll
  for (int rr = 0; rr < 4; ++rr) {
    float iv = sigf(gi[rr]);
    float fv = sigf(gf[rr]);
    float gv = tanhf_(gg[rr]);
    float ov = sigf(go[rr]);
    float cN = fv * c[rr] + iv * gv;
    c[rr] = cN;
    float hv = ov * tanhf_(cN);
    const int hrow = mt * 16 + lh * 4 + rr;
    *(__bf16*)(hnxt + hrow * 128 + ((hcol * 2) ^ ((hrow & 7) << 4))) = (__bf16)hv;
    if (dostore) out[ob[rr] + soff] = hv;
  }
}

__global__ __launch_bounds__(256, 4) void k_main(
    const float* __restrict__ x,
    const float* __restrict__ W1, const float* __restrict__ W2, const float* __restrict__ W3,
    const float* __restrict__ g2, const float* __restrict__ be2,
    const float* __restrict__ b3,
    const float* __restrict__ Wih, const float* __restrict__ Whh,
    const float* __restrict__ bih, const float* __restrict__ bhh,
    const float* __restrict__ part2, const float* __restrict__ sc1sh1,
    float* __restrict__ out)
{
  // LDS layout (34304 B -> 4 blocks/CU):
  //   encb [0,12288)      : [3][32][64] bf16, row XOR-swizzled
  //   hb   [12288,20480)  : [2][32][64] bf16 ping-pong; w1t (8KB) overlays (dead before LSTM)
  //   w2t  [20480,24576), w3t [24576,32768), scal [32768,34304)
  __shared__ __align__(16) char smem[34304];
  char*  encb = smem;
  char*  hb   = smem + 12288;
  float* w1t  = (float*)(smem + 12288);
  float* w2t  = (float*)(smem + 20480);
  float* w3t  = (float*)(smem + 24576);
  float* scal = (float*)(smem + 32768);

  const int tid = threadIdx.x;
  const int row0 = blockIdx.x * 32;

  #pragma unroll
  for (int i = 0; i < 8; ++i) { int e = tid * 8 + i; w1t[(e & 63) * 32 + (e >> 6)] = W1[e]; }
  #pragma unroll
  for (int i = 0; i < 4; ++i) { int e = tid * 4 + i; w2t[(e & 31) * 32 + (e >> 5)] = W2[e]; }
  #pragma unroll
  for (int i = 0; i < 8; ++i) { int e = tid * 8 + i; w3t[(e & 31) * 64 + (e >> 5)] = W3[e]; }
  if (tid < 96) {          // reduce part2 -> scales2
    const int t = tid >> 5, j = tid & 31;
    float s = 0.f, q = 0.f;
    for (int c = 0; c < 256; ++c) {
      const float* p = part2 + (t * 256 + c) * 64 + j;
      s += p[0]; q += p[32];
    }
    float mean = s * (1.f / NB);
    float var  = q * (1.f / NB) - mean * mean;
    float sc = g2[j] * rsqrtf(var + 1e-5f);
    scal[192 + t * 64 + j] = sc;
    scal[192 + t * 64 + 32 + j] = be2[j] - mean * sc;
  }
  if (tid < 192) scal[tid] = sc1sh1[tid];
  __syncthreads();

  if (tid < 96) {
    const int t = tid >> 5, r = tid & 31;
    const f4_t* xrow = (const f4_t*)(x + ((size_t)t * NB + row0 + r) * 64);
    f4_t acc[8];
    #pragma unroll
    for (int jq = 0; jq < 8; ++jq) acc[jq] = (f4_t){0.f, 0.f, 0.f, 0.f};
    #pragma unroll
    for (int k4 = 0; k4 < 16; ++k4) {
      f4_t xc = xrow[k4];
      #pragma unroll
      for (int kk = 0; kk < 4; ++kk) {
        const float xs = xc[kk];
        const f4_t* wr = (const f4_t*)&w1t[(k4 * 4 + kk) * 32];
        #pragma unroll
        for (int jq = 0; jq < 8; ++jq) acc[jq] += xs * wr[jq];
      }
    }
    float a1[32];
    #pragma unroll
    for (int jq = 0; jq < 8; ++jq)
      #pragma unroll
      for (int c = 0; c < 4; ++c) {
        int j = jq * 4 + c;
        a1[j] = fmaxf(acc[jq][c] * scal[t * 64 + j] + scal[t * 64 + 32 + j], 0.f);
      }
    f4_t acc2[8];
    #pragma unroll
    for (int jq = 0; jq < 8; ++jq) acc2[jq] = (f4_t){0.f, 0.f, 0.f, 0.f};
    #pragma unroll
    for (int k = 0; k < 32; ++k) {
      const float a = a1[k];
      const f4_t* wr = (const f4_t*)&w2t[k * 32];
      #pragma unroll
      for (int jq = 0; jq < 8; ++jq) acc2[jq] += a * wr[jq];
    }
    float a2[32];
    #pragma unroll
    for (int jq = 0; jq < 8; ++jq)
      #pragma unroll
      for (int c = 0; c < 4; ++c) {
        int j = jq * 4 + c;
        a2[j] = fmaxf(acc2[jq][c] * scal[192 + t * 64 + j] + scal[192 + t * 64 + 32 + j], 0.f);
      }
    f4_t acc3[16];
    #pragma unroll
    for (int jq = 0; jq < 16; ++jq) acc3[jq] = (f4_t){0.f, 0.f, 0.f, 0.f};
    #pragma unroll
    for (int k = 0; k < 32; ++k) {
      const float a = a2[k];
      const f4_t* wr = (const f4_t*)&w3t[k * 64];
      #pragma unroll
      for (int jq = 0; jq < 16; ++jq) acc3[jq] += a * wr[jq];
    }
    const f4_t* b3v = (const f4_t*)b3;
    char* encrow = encb + t * 4096 + r * 128;
    const int swb = (r & 7) << 4;
    #pragma unroll
    for (int c = 0; c < 8; ++c) {
      f4_t lo = acc3[2 * c]     + b3v[2 * c];
      f4_t hi = acc3[2 * c + 1] + b3v[2 * c + 1];
      bf8_t e8;
      e8[0] = (__bf16)lo[0]; e8[1] = (__bf16)lo[1]; e8[2] = (__bf16)lo[2]; e8[3] = (__bf16)lo[3];
      e8[4] = (__bf16)hi[0]; e8[5] = (__bf16)hi[1]; e8[6] = (__bf16)hi[2]; e8[7] = (__bf16)hi[3];
      *(bf8_t*)(encrow + ((c * 16) ^ swb)) = e8;
    }
  }
  __syncthreads();

  // ---------- LSTM ----------
  const int wn = tid >> 6;
  const int l = tid & 63;
  const int l15 = l & 15, lh = l >> 4;
  const int hcol = wn * 16 + l15;
  const int nbase = wn * 16 + l15;

  float bini4[4];
  #pragma unroll
  for (int g = 0; g < 4; ++g) {
    int n = g * 64 + nbase;
    bini4[g] = bih[n] + bhh[n];
  }
  f4_t cst[2];
  cst[0] = (f4_t){0.f, 0.f, 0.f, 0.f};
  cst[1] = (f4_t){0.f, 0.f, 0.f, 0.f};
  int ob[2][4];
  #pragma unroll
  for (int mt = 0; mt < 2; ++mt)
    #pragma unroll
    for (int rr = 0; rr < 4; ++rr)
      ob[mt][rr] = (row0 + mt * 16 + lh * 4 + rr) * 1600 + hcol;

  // ---- loop 1: s = 0..3 (x-input from enc; +h via Whh for s>0) ----
  {
    bf8_t wcf[4][4];      // [gate][ktile]: kt 0,1 = Wih, kt 2,3 = Whh
    #pragma unroll
    for (int g = 0; g < 4; ++g) {
      const int n = g * 64 + nbase;
      #pragma unroll
      for (int kt = 0; kt < 4; ++kt) {
        const float* src = ((kt < 2) ? Wih : Whh) + n * 64 + (kt & 1) * 32 + lh * 8;
        f4_t a = *(const f4_t*)src, b = *(const f4_t*)(src + 4);
        bf8_t w;
        w[0] = (__bf16)a[0]; w[1] = (__bf16)a[1]; w[2] = (__bf16)a[2]; w[3] = (__bf16)a[3];
        w[4] = (__bf16)b[0]; w[5] = (__bf16)b[1]; w[6] = (__bf16)b[2]; w[7] = (__bf16)b[3];
        wcf[g][kt] = w;
      }
    }
    for (int s = 0; s < 4; ++s) {
      char* hcur = hb + (s & 1) * 4096;
      char* hnxt = hb + ((s + 1) & 1) * 4096;
      const char* xsrc = encb + ((s < 3) ? s : 2) * 4096;
      #pragma unroll
      for (int mt = 0; mt < 2; ++mt) {
        const int rowb = mt * 16 + l15;
        const int swz = (rowb & 7) << 4;
        const int cb = lh * 16;
        const char* xr = xsrc + rowb * 128;
        f4_t gi = (f4_t){bini4[0], bini4[0], bini4[0], bini4[0]};
        f4_t gf = (f4_t){bini4[1], bini4[1], bini4[1], bini4[1]};
        f4_t gg = (f4_t){bini4[2], bini4[2], bini4[2], bini4[2]};
        f4_t go = (f4_t){bini4[3], bini4[3], bini4[3], bini4[3]};
        bf8_t av0 = *(const bf8_t*)(xr + (cb ^ swz));
        bf8_t av1 = *(const bf8_t*)(xr + ((64 + cb) ^ swz));
        gi = MFMA16(av0, wcf[0][0], gi); gf = MFMA16(av0, wcf[1][0], gf);
        gg = MFMA16(av0, wcf[2][0], gg); go = MFMA16(av0, wcf[3][0], go);
        gi = MFMA16(av1, wcf[0][1], gi); gf = MFMA16(av1, wcf[1][1], gf);
        gg = MFMA16(av1, wcf[2][1], gg); go = MFMA16(av1, wcf[3][1], go);
        if (s > 0) {
          const char* hr = hcur + rowb * 128;
          bf8_t av2 = *(const bf8_t*)(hr + (cb ^ swz));
          bf8_t av3 = *(const bf8_t*)(hr + ((64 + cb) ^ swz));
          gi = MFMA16(av2, wcf[0][2], gi); gf = MFMA16(av2, wcf[1][2], gf);
          gg = MFMA16(av2, wcf[2][2], gg); go = MFMA16(av2, wcf[3][2], go);
          gi = MFMA16(av3, wcf[0][3], gi); gf = MFMA16(av3, wcf[1][3], gf);
          gg = MFMA16(av3, wcf[2][3], gg); go = MFMA16(av3, wcf[3][3], go);
        }
        cell_update(gi, gf, gg, go, cst[mt], hnxt, out, ob[mt], mt, lh, hcol, s == 3, 0);
      }
      __syncthreads();
    }
  }

  // ---- loop 2: s = 4..27 (input == h; fused Wih+Whh) ----
  {
    bf8_t wsm[4][2];
    #pragma unroll
    for (int g = 0; g < 4; ++g) {
      const int n = g * 64 + nbase;
      #pragma unroll
      for (int kt = 0; kt < 2; ++kt) {
        const float* s0 = Wih + n * 64 + kt * 32 + lh * 8;
        const float* s1p = Whh + n * 64 + kt * 32 + lh * 8;
        f4_t a = *(const f4_t*)s0 + *(const f4_t*)s1p;
        f4_t b = *(const f4_t*)(s0 + 4) + *(const f4_t*)(s1p + 4);
        bf8_t w;
        w[0] = (__bf16)a[0]; w[1] = (__bf16)a[1]; w[2] = (__bf16)a[2]; w[3] = (__bf16)a[3];
        w[4] = (__bf16)b[0]; w[5] = (__bf16)b[1]; w[6] = (__bf16)b[2]; w[7] = (__bf16)b[3];
        wsm[g][kt] = w;
      }
    }
    for (int s = 4; s < 28; ++s) {
      char* hcur = hb + (s & 1) * 4096;
      char* hnxt = hb + ((s + 1) & 1) * 4096;
      const int soff = (s - 3) * 64;
      #pragma unroll
      for (int mt = 0; mt < 2; ++mt) {
        const int rowb = mt * 16 + l15;
        const int swz = (rowb & 7) << 4;
        const int cb = lh * 16;
        const char* xr = hcur + rowb * 128;
        f4_t gi = (f4_t){bini4[0], bini4[0], bini4[0], bini4[0]};
        f4_t gf = (f4_t){bini4[1], bini4[1], bini4[1], bini4[1]};
        f4_t gg = (f4_t){bini4[2], bini4[2], bini4[2], bini4[2]};
        f4_t go = (f4_t){bini4[3], bini4[3], bini4[3], bini4[3]};
        bf8_t av0 = *(const bf8_t*)(xr + (cb ^ swz));
        bf8_t av1 = *(const bf8_t*)(xr + ((64 + cb) ^ swz));
        gi = MFMA16(av0, wsm[0][0], gi); gf = MFMA16(av0, wsm[1][0], gf);
        gg = MFMA16(av0, wsm[2][0], gg); go = MFMA16(av0, wsm[3][0], go);
        gi = MFMA16(av1, wsm[0][1], gi); gf = MFMA16(av1, wsm[1][1], gf);
        gg = MFMA16(av1, wsm[2][1], gg); go = MFMA16(av1, wsm[3][1], go);
        cell_update(gi, gf, gg, go, cst[mt], hnxt, out, ob[mt], mt, lh, hcol, true, soff);
      }
      __syncthreads();
    }
  }
}

extern "C" void kernel_launch(void* const* d_in, const int* in_sizes, int n_in,
                              void* d_out, int out_size, void* d_ws, size_t ws_size,
                              hipStream_t stream) {
  (void)in_sizes; (void)n_in; (void)out_size; (void)ws_size;
  const float* x   = (const float*)d_in[0];
  const float* W1  = (const float*)d_in[1];
  const float* g1  = (const float*)d_in[3];
  const float* be1 = (const float*)d_in[4];
  const float* W2  = (const float*)d_in[5];
  const float* g2  = (const float*)d_in[7];
  const float* be2 = (const float*)d_in[8];
  const float* W3  = (const float*)d_in[9];
  const float* b3  = (const float*)d_in[10];
  const float* Wih = (const float*)d_in[11];
  const float* Whh = (const float*)d_in[12];
  const float* bih = (const float*)d_in[13];
  const float* bhh = (const float*)d_in[14];
  float* out = (float*)d_out;

  char* ws = (char*)d_ws;
  float* part1  = (float*)ws;                 // [3][256][2][32] = 196608 B
  float* part2  = (float*)(ws + 196608);      // same
  float* sc1sh1 = (float*)(ws + 393216);      // [3][64]

  kA<<<768, 128, 0, stream>>>(x, W1, part1);
  kC<<<768, 128, 0, stream>>>(x, W1, W2, g1, be1, part1, part2, sc1sh1);
  k_main<<<1024, 256, 0, stream>>>(x, W1, W2, W3, g2, be2, b3,
                                   Wih, Whh, bih, bhh, part2, sc1sh1, out);
}